// Round 2
// baseline (96.904 us; speedup 1.0000x reference)
//
#include <hip/hip_runtime.h>
#include <utility>

// Polyphase resample up=3 down=2, N=2097152, L=129 taps, start=(L-1)/2=64.
// out[3j+0] = 3 * sum_i x[21+2j-i] * h[1+3i]   (i in [0,43))
// out[3j+1] = 3 * sum_i x[22+2j-i] * h[0+3i]
// out[3j+2] = 3 * sum_i x[22+2j-i] * h[2+3i]
// Out-of-range x indices are zero (zero-stuffed conv boundary).

#define N_SIG   2097152
#define L_FILT  129
#define NTAPS   43          // taps per phase
#define G       8           // output groups per thread
#define BLK     256
#define GROUPS_PER_BLK (BLK * G)            // 2048 groups -> 6144 outputs/block
#define TILE_Q  4160                        // unpadded tile floats (multiple of 4)
#define TILE_P  (TILE_Q + (TILE_Q / 16) * 4) // 5200 padded (4 pad words per 16)

// One tap, I is a compile-time constant -> every w[] index is constant
// regardless of the unroller's cost model (R1 post-mortem: 84us consistent
// with w[64] spilling to scratch when the 43x8 loop nest isn't fully
// unrolled; this expansion makes spill structurally impossible).
template <int I>
__device__ __forceinline__ void tap(const float* __restrict__ hs,
                                    const float (&w)[64], float (&acc)[3 * G]) {
    const float h0 = hs[3 * I + 0];
    const float h1 = hs[3 * I + 1];
    const float h2 = hs[3 * I + 2];
#pragma unroll
    for (int g = 0; g < G; ++g) {
        const float xa = w[45 + 2 * g - I];
        const float xb = w[46 + 2 * g - I];
        acc[3 * g + 0] += xa * h1;
        acc[3 * g + 1] += xb * h0;
        acc[3 * g + 2] += xb * h2;
    }
}

template <int... Is>
__device__ __forceinline__ void all_taps(const float* __restrict__ hs,
                                         const float (&w)[64], float (&acc)[3 * G],
                                         std::integer_sequence<int, Is...>) {
    ((tap<Is>(hs, w, acc)), ...);
}

__global__ __launch_bounds__(BLK) void poly_kernel(
    const float* __restrict__ x, const float* __restrict__ h,
    float* __restrict__ out, int n_out)
{
    __shared__ float xs[TILE_P];
    __shared__ float hs[L_FILT];

    const int tid = threadIdx.x;
    const int b   = blockIdx.x;

    // Stage filter taps, folding in the gain `up`=3 once.
    if (tid < L_FILT) hs[tid] = 3.0f * h[tid];

    // x-tile base (x index of logical tile word q=0), 4-float aligned.
    // First thread's window starts at x[4096*b - 21]; align down to
    // 4096*b - 24 so windows sit at logical word 16*tid + 3.
    const int tb = 4096 * b - 24;

    // Coalesced staging with zero-pad at array edges.
    // Padded layout: logical word q lives at q + 4*(q>>4); float4s stay
    // contiguous and window reads get lane-stride 20 words -> all 32 banks.
    for (int q4 = tid; q4 < TILE_Q / 4; q4 += BLK) {
        const int gx = tb + 4 * q4;
        float4 v;
        if (gx >= 0 && gx + 3 < N_SIG) {
            v = *(const float4*)(x + gx);
        } else {
            v.x = (gx     >= 0 && gx     < N_SIG) ? x[gx]     : 0.0f;
            v.y = (gx + 1 >= 0 && gx + 1 < N_SIG) ? x[gx + 1] : 0.0f;
            v.z = (gx + 2 >= 0 && gx + 2 < N_SIG) ? x[gx + 2] : 0.0f;
            v.w = (gx + 3 >= 0 && gx + 3 < N_SIG) ? x[gx + 3] : 0.0f;
        }
        const int p = 4 * q4 + 4 * (q4 >> 2);
        *(float4*)(xs + p) = v;
    }
    __syncthreads();

    // Register window: logical words [16*tid, 16*tid+64), i.e.
    // w[d] = x[tb + 16*tid + d]. Needed range d in [3, 60].
    float w[64];
#pragma unroll
    for (int k = 0; k < 16; ++k) {
        const int p = 20 * tid + 4 * k + 4 * (k >> 2);
        const float4 v = *(const float4*)(xs + p);
        w[4 * k + 0] = v.x; w[4 * k + 1] = v.y;
        w[4 * k + 2] = v.z; w[4 * k + 3] = v.w;
    }

    float acc[3 * G];
#pragma unroll
    for (int k = 0; k < 3 * G; ++k) acc[k] = 0.0f;

    // Thread handles groups j = 2048*b + 8*tid + g:
    // x[21+2j-i] -> w[45 + 2g - i], x[22+2j-i] -> w[46 + 2g - i].
    all_taps(hs, w, acc, std::make_integer_sequence<int, NTAPS>{});

    // 24 contiguous outputs per thread, 16B-aligned.
    const long ob = (long)GROUPS_PER_BLK * b * 3 + (long)(3 * G) * tid;
#pragma unroll
    for (int k = 0; k < 6; ++k) {
        if (ob + 4 * k + 3 < (long)n_out) {
            *(float4*)(out + ob + 4 * k) =
                make_float4(acc[4 * k + 0], acc[4 * k + 1],
                            acc[4 * k + 2], acc[4 * k + 3]);
        }
    }
}

extern "C" void kernel_launch(void* const* d_in, const int* in_sizes, int n_in,
                              void* d_out, int out_size, void* d_ws, size_t ws_size,
                              hipStream_t stream) {
    const float* x = (const float*)d_in[0];
    const float* h = (const float*)d_in[1];
    float* out = (float*)d_out;
    const int blocks = (out_size + 3 * GROUPS_PER_BLK - 1) / (3 * GROUPS_PER_BLK);
    poly_kernel<<<blocks, BLK, 0, stream>>>(x, h, out, out_size);
}

// Round 3
// 70.438 us; speedup vs baseline: 1.3757x; 1.3757x over previous
//
#include <hip/hip_runtime.h>

// Polyphase resample up=3 down=2, N=2097152, L=129 taps, start=(L-1)/2=64.
// out[3j+0] = 3 * sum_i x[21+2j-i] * h[1+3i]   (i in [0,43))
// out[3j+1] = 3 * sum_i x[22+2j-i] * h[0+3i]
// out[3j+2] = 3 * sum_i x[22+2j-i] * h[2+3i]
// (formula verified: R1/R2 passed with absmax 0.25)
//
// R2 post-mortem: VGPR=256 + 23MB spill writes — the fully-unrolled 43x8
// block hoisted everything. New structure: ROLLED chunk loop (runtime i0,
// no hoisting), per-chunk 15-float LDS->reg window with COMPILE-TIME reg
// indices, h via wave-uniform global reads (s_load -> SGPRs, 0 VGPR cost).

#define N_SIG   2097152
#define L_FILT  129
#define NTAPS   43
#define G       4            // output groups per thread (12 outputs)
#define BLK     256
#define GROUPS_PER_BLK (BLK * G)             // 1024 groups -> 3072 outputs/block
#define TILE_Q  2112                         // logical tile words (covers q in [0,2093))
#define TILE_P  (TILE_Q + TILE_Q / 8)        // 2376: pad 1 word per 8 -> lane
                                             // stride 9 (odd) -> conflict-free

// One tap-chunk of U taps starting at runtime i0 (i0+U-1 determines window
// base D = 45-(i0+U-1); R = D&7 must be a compile-time constant so the
// per-k pad offsets ((R+k)>>3) are immediates).
template <int U, int R>
__device__ __forceinline__ void do_chunk(const float* __restrict__ xs,
                                         const float* __restrict__ h,
                                         int i0, int tid, float (&acc)[3 * G]) {
    const int D = 45 - (i0 + U - 1);          // window base in d-space (runtime)
    const int pb = 9 * tid + 9 * (D >> 3) + R; // padded word addr of window[0]
    float wz[U + 7];                           // window: d in [D, D+U+6]
#pragma unroll
    for (int k = 0; k < U + 7; ++k)
        wz[k] = xs[pb + k + ((R + k) >> 3)];   // const offsets, stride-9 lanes
#pragma unroll
    for (int u = 0; u < U; ++u) {
        // wave-uniform indices -> scalar loads, SGPR operands in the FMAs
        const float h0 = h[3 * (i0 + u) + 0];
        const float h1 = h[3 * (i0 + u) + 1];
        const float h2 = h[3 * (i0 + u) + 2];
#pragma unroll
        for (int g = 0; g < G; ++g) {
            const float xa = wz[(U - 1 - u) + 2 * g];      // x[21+2j-i]
            const float xb = wz[(U - 1 - u) + 2 * g + 1];  // x[22+2j-i]
            acc[3 * g + 0] += xa * h1;
            acc[3 * g + 1] += xb * h0;
            acc[3 * g + 2] += xb * h2;
        }
    }
}

__global__ __launch_bounds__(BLK, 4) void poly_kernel(
    const float* __restrict__ x, const float* __restrict__ h,
    float* __restrict__ out, int n_out)
{
    __shared__ float xs[TILE_P];

    const int tid = threadIdx.x;
    const int b   = blockIdx.x;

    // Tile base: local group jl uses x[2*GPB*b + {21,22} + 2*jl - i];
    // tb = 2048b - 24 puts needed words at q = 45 + 2*jl - i in [3, 2093).
    const int tb = 2 * GROUPS_PER_BLK * b - 24;

    // Coalesced staging with zero-pad at edges. Logical word q lives at
    // p = q + (q>>3); a float4 at q%8 in {0,4} never straddles a pad.
    for (int q4 = tid; q4 < TILE_Q / 4; q4 += BLK) {
        const int gx = tb + 4 * q4;
        float4 v;
        if (gx >= 0 && gx + 3 < N_SIG) {
            v = *(const float4*)(x + gx);
        } else {
            v.x = (gx     >= 0 && gx     < N_SIG) ? x[gx]     : 0.0f;
            v.y = (gx + 1 >= 0 && gx + 1 < N_SIG) ? x[gx + 1] : 0.0f;
            v.z = (gx + 2 >= 0 && gx + 2 < N_SIG) ? x[gx + 2] : 0.0f;
            v.w = (gx + 3 >= 0 && gx + 3 < N_SIG) ? x[gx + 3] : 0.0f;
        }
        const int q = 4 * q4;
        const int p = q + (q >> 3);
        xs[p + 0] = v.x; xs[p + 1] = v.y; xs[p + 2] = v.z; xs[p + 3] = v.w;
    }
    __syncthreads();

    float acc[3 * G];
#pragma unroll
    for (int k = 0; k < 3 * G; ++k) acc[k] = 0.0f;

    // 5 chunks of 8 taps (D = 38-i0, D&7 == 6 for all) + remainder of 3
    // (D = 3). Rolled loop: no hoisting across chunks -> bounded pressure.
#pragma unroll 1
    for (int i0 = 0; i0 < 40; i0 += 8)
        do_chunk<8, 6>(xs, h, i0, tid, acc);
    do_chunk<3, 3>(xs, h, 40, tid, acc);

    // 12 contiguous outputs per thread (16B-aligned); fold the up=3 gain here.
    const int ob = 3 * GROUPS_PER_BLK * b + 3 * G * tid;
#pragma unroll
    for (int k = 0; k < 3; ++k) {
        if (ob + 4 * k + 3 < n_out) {
            *(float4*)(out + ob + 4 * k) =
                make_float4(3.0f * acc[4 * k + 0], 3.0f * acc[4 * k + 1],
                            3.0f * acc[4 * k + 2], 3.0f * acc[4 * k + 3]);
        }
    }
}

extern "C" void kernel_launch(void* const* d_in, const int* in_sizes, int n_in,
                              void* d_out, int out_size, void* d_ws, size_t ws_size,
                              hipStream_t stream) {
    const float* x = (const float*)d_in[0];
    const float* h = (const float*)d_in[1];
    float* out = (float*)d_out;
    const int blocks = (out_size + 3 * GROUPS_PER_BLK - 1) / (3 * GROUPS_PER_BLK);
    poly_kernel<<<blocks, BLK, 0, stream>>>(x, h, out, out_size);
}